// Round 2
// baseline (1178.452 us; speedup 1.0000x reference)
//
#include <hip/hip_runtime.h>
#include <math.h>

#define SB 512
#define NB 128
#define NE 100
#define HD 64
#define NK 9

__device__ __forceinline__ float frcp(float x) { return __builtin_amdgcn_rcpf(x); }
__device__ __forceinline__ float fsig(float x) { return frcp(1.0f + __expf(-x)); }
__device__ __forceinline__ float ftanh(float x) {
    float t = __expf(-2.0f * fabsf(x));
    float r = (1.0f - t) * frcp(1.0f + t);
    return copysignf(r, x);
}
__device__ __forceinline__ float bf2f(unsigned short u) {
    return __uint_as_float(((unsigned)u) << 16);
}
__device__ __forceinline__ unsigned short f2bf(float f) {
    unsigned x = __float_as_uint(f);
    return (unsigned short)((x + 0x7FFFu + ((x >> 16) & 1u)) >> 16);
}

// ---------------------------------------------------------------------------
// prep: W2[col][k] (col = dir*256 + j*4 + g -> Wih row g*64+j), bias2, tagsT
// ---------------------------------------------------------------------------
__global__ void prep_kernel(const int* __restrict__ tags,
                            const float* __restrict__ Wih_f, const float* __restrict__ Wih_bb,
                            const float* __restrict__ b_f, const float* __restrict__ b_bb,
                            float* __restrict__ W2, float* __restrict__ bias2,
                            int* __restrict__ tagsT)
{
    int idx = blockIdx.x * 256 + threadIdx.x;
    if (idx < 51200) {
        int col = idx / 100, k = idx % 100;
        int dir = col >> 8, r = col & 255, j = r >> 2, g = r & 3;
        const float* W = dir ? Wih_bb : Wih_f;
        W2[idx] = W[(g * 64 + j) * 100 + k];
    } else if (idx < 51712) {
        int col = idx - 51200;
        int dir = col >> 8, r = col & 255, j = r >> 2, g = r & 3;
        bias2[col] = (dir ? b_bb : b_f)[g * 64 + j];
    } else if (idx < 117248) {
        int i = idx - 51712;
        int t = i >> 7, b = i & 127;
        tagsT[i] = tags[b * SB + t] - 1;
    }
}

// ---------------------------------------------------------------------------
// input GEMM: xg[tb][512] (bf16) = emb[token(t,b)] . W2^T + bias2
// tile 128 tb-rows (= all b for one t) x 128 cols, 8x8 register blocking
// ---------------------------------------------------------------------------
__global__ __launch_bounds__(256, 1) void gemm_kernel(
    const int* __restrict__ inputs, const float* __restrict__ emb,
    const float* __restrict__ W2, const float* __restrict__ bias2,
    unsigned short* __restrict__ xg)
{
    __shared__ __align__(16) float sE[128 * 100];
    __shared__ __align__(16) float sW[128 * 100];
    const int bx = blockIdx.x;
    const int tt = bx >> 2;          // t index
    const int cb = (bx & 3) * 128;   // col base
    const int tid = threadIdx.x;

    for (int idx = tid; idx < 3200; idx += 256) {
        int row = idx / 25, c4 = idx % 25;
        int token = inputs[row * SB + tt];
        ((float4*)sE)[row * 25 + c4] = ((const float4*)emb)[token * 25 + c4];
    }
    for (int idx = tid; idx < 3200; idx += 256) {
        ((float4*)sW)[idx] = ((const float4*)W2)[cb * 25 + idx];
    }
    __syncthreads();

    const int tx = tid & 15;   // col group: cols cb + tx + 16*i
    const int ty = tid >> 4;   // row group: rows ty + 16*r
    float acc[8][8];
    #pragma unroll
    for (int r = 0; r < 8; ++r)
        #pragma unroll
        for (int i = 0; i < 8; ++i) acc[r][i] = 0.f;

    for (int kg = 0; kg < 25; ++kg) {
        float4 e[8], w[8];
        #pragma unroll
        for (int r = 0; r < 8; ++r) e[r] = ((const float4*)sE)[(ty + 16 * r) * 25 + kg];
        #pragma unroll
        for (int i = 0; i < 8; ++i) w[i] = ((const float4*)sW)[(tx + 16 * i) * 25 + kg];
        #pragma unroll
        for (int r = 0; r < 8; ++r)
            #pragma unroll
            for (int i = 0; i < 8; ++i)
                acc[r][i] += e[r].x * w[i].x + e[r].y * w[i].y +
                             e[r].z * w[i].z + e[r].w * w[i].w;
    }

    #pragma unroll
    for (int i = 0; i < 8; ++i) {
        int col = cb + tx + 16 * i;
        float bc = bias2[col];
        #pragma unroll
        for (int r = 0; r < 8; ++r) {
            int tb = tt * NB + ty + 16 * r;
            xg[(size_t)tb * 512 + col] = f2bf(acc[r][i] + bc);
        }
    }
}

// ---------------------------------------------------------------------------
// LSTM recurrence: 256 blocks (b,dir) x 64 lanes (1 wave). Lane j = unit j,
// holds all 4 Whh gate-rows in VGPRs; h broadcast via LDS (wave-synchronous).
// ---------------------------------------------------------------------------
__global__ __launch_bounds__(64, 1) void lstm_kernel(
    const unsigned short* __restrict__ xg,
    const float* __restrict__ Whh_f, const float* __restrict__ Whh_bb,
    float* __restrict__ h_all)
{
    const int blk = blockIdx.x;
    const int b = blk & (NB - 1);
    const int dir = blk >> 7;
    const float* Whh = dir ? Whh_bb : Whh_f;
    const int j = threadIdx.x;

    float4 wi[16], wf[16], wg[16], wo[16];
    const float4* W4 = (const float4*)Whh;  // row r -> W4[r*16 + k]
    #pragma unroll
    for (int k = 0; k < 16; ++k) {
        wi[k] = W4[(0 * 64 + j) * 16 + k];
        wf[k] = W4[(1 * 64 + j) * 16 + k];
        wg[k] = W4[(2 * 64 + j) * 16 + k];
        wo[k] = W4[(3 * 64 + j) * 16 + k];
    }
    __shared__ __align__(16) float hbuf[64];
    hbuf[j] = 0.f;
    float c = 0.f;
    const int xoff = dir * 256 + j * 4;
    __syncthreads();

#define XG_LD(s) (*(const ushort4*)(xg + ((size_t)((dir ? (SB - 1 - (s)) : (s)) * NB + b) * 512 + xoff)))
    ushort4 p0 = XG_LD(0), p1 = XG_LD(1);

    for (int s = 0; s < SB; ++s) {
        const int t = dir ? (SB - 1 - s) : s;
        float ai = bf2f(p0.x), af = bf2f(p0.y), ag = bf2f(p0.z), ao = bf2f(p0.w);
        p0 = p1;
        if (s + 2 < SB) p1 = XG_LD(s + 2);

        const float4* h4 = (const float4*)hbuf;
        #pragma unroll
        for (int k = 0; k < 16; ++k) {
            float4 h = h4[k];
            ai += h.x * wi[k].x + h.y * wi[k].y + h.z * wi[k].z + h.w * wi[k].w;
            af += h.x * wf[k].x + h.y * wf[k].y + h.z * wf[k].z + h.w * wf[k].w;
            ag += h.x * wg[k].x + h.y * wg[k].y + h.z * wg[k].z + h.w * wg[k].w;
            ao += h.x * wo[k].x + h.y * wo[k].y + h.z * wo[k].z + h.w * wo[k].w;
        }
        float ig = fsig(ai), fg = fsig(af), gg = ftanh(ag), og = fsig(ao);
        c = fg * c + ig * gg;
        float h = og * ftanh(c);
        h_all[((size_t)t * NB + b) * 128 + dir * HD + j] = h;
        __syncthreads();   // single wave: cheap; orders hbuf rewrite vs reads
        hbuf[j] = h;
    }
#undef XG_LD
}

// ---------------------------------------------------------------------------
// projection: em2[t][k][b] = h_all[t][b][:] . W_out[k+1][:] + b_out[k+1]
// ---------------------------------------------------------------------------
__global__ __launch_bounds__(128) void proj_kernel(
    const float* __restrict__ h_all, const float* __restrict__ W_out,
    const float* __restrict__ b_out, float* __restrict__ em2)
{
    __shared__ __align__(16) float sWo[9 * 128];
    __shared__ float sb[9];
    const int t = blockIdx.x, b = threadIdx.x;
    for (int idx = b; idx < 1152; idx += 128) sWo[idx] = W_out[128 + idx];
    if (b < 9) sb[b] = b_out[1 + b];
    __syncthreads();

    const float4* h4 = (const float4*)(h_all + ((size_t)t * NB + b) * 128);
    float acc[9];
    #pragma unroll
    for (int k = 0; k < 9; ++k) acc[k] = 0.f;
    for (int q = 0; q < 32; ++q) {
        float4 hv = h4[q];
        #pragma unroll
        for (int k = 0; k < 9; ++k) {
            float4 wv = ((const float4*)sWo)[k * 32 + q];
            acc[k] += hv.x * wv.x + hv.y * wv.y + hv.z * wv.z + hv.w * wv.w;
        }
    }
    #pragma unroll
    for (int k = 0; k < 9; ++k)
        em2[((size_t)t * 9 + k) * NB + b] = acc[k] + sb[k];
}

// ---------------------------------------------------------------------------
// CRF: lane b = one batch chain. Linear-space alpha, exp(trans) in regs,
// renorm every 8 steps. Coalesced em2[t][k][b] / tagsT[t][b] + 1-step prefetch.
// ---------------------------------------------------------------------------
__device__ __forceinline__ float pick9(const float e[9], int k) {
    float r = e[0];
    r = (k == 1) ? e[1] : r;  r = (k == 2) ? e[2] : r;
    r = (k == 3) ? e[3] : r;  r = (k == 4) ? e[4] : r;
    r = (k == 5) ? e[5] : r;  r = (k == 6) ? e[6] : r;
    r = (k == 7) ? e[7] : r;  r = (k == 8) ? e[8] : r;
    return r;
}

__global__ __launch_bounds__(128, 1) void crf_kernel(
    const float* __restrict__ em2, const int* __restrict__ tagsT,
    const float* __restrict__ startv, const float* __restrict__ endv,
    const float* __restrict__ trans, float* __restrict__ out)
{
    const int b = threadIdx.x;
    float E[81];
    #pragma unroll
    for (int i = 0; i < 81; ++i) E[i] = __expf(trans[i]);

    float cur[9];
    #pragma unroll
    for (int k = 0; k < 9; ++k) cur[k] = em2[(size_t)k * NB + b];
    int tg = tagsT[b];
    float score = startv[tg] + pick9(cur, tg);
    float A[9], M = 0.f;
    #pragma unroll
    for (int k = 0; k < 9; ++k) A[k] = __expf(startv[k] + cur[k]);

    // 1-deep prefetch buffers
    float nb[9]; int ndt;
    #pragma unroll
    for (int k = 0; k < 9; ++k) nb[k] = em2[((size_t)9 + k) * NB + b];
    ndt = tagsT[NB + b];

    for (int t = 1; t < SB; ++t) {
        float e[9]; int etg = ndt;
        #pragma unroll
        for (int k = 0; k < 9; ++k) e[k] = nb[k];
        if (t + 1 < SB) {
            #pragma unroll
            for (int k = 0; k < 9; ++k) nb[k] = em2[((size_t)(t + 1) * 9 + k) * NB + b];
            ndt = tagsT[(t + 1) * NB + b];
        }
        score += trans[tg * 9 + etg] + pick9(e, etg);
        tg = etg;

        float snew[9];
        #pragma unroll
        for (int jj = 0; jj < 9; ++jj) snew[jj] = 0.f;
        #pragma unroll
        for (int i = 0; i < 9; ++i)
            #pragma unroll
            for (int jj = 0; jj < 9; ++jj) snew[jj] += A[i] * E[i * 9 + jj];
        #pragma unroll
        for (int jj = 0; jj < 9; ++jj) A[jj] = snew[jj] * __expf(e[jj]);

        if ((t & 7) == 0) {
            float mx = A[0];
            #pragma unroll
            for (int jj = 1; jj < 9; ++jj) mx = fmaxf(mx, A[jj]);
            M += __logf(mx);
            float r = frcp(mx);
            #pragma unroll
            for (int jj = 0; jj < 9; ++jj) A[jj] *= r;
        }
    }
    score += endv[tg];
    float Z = 0.f;
    #pragma unroll
    for (int jj = 0; jj < 9; ++jj) Z += A[jj] * __expf(endv[jj]);
    float part = M + __logf(Z) - score;

    #pragma unroll
    for (int off = 32; off > 0; off >>= 1) part += __shfl_down(part, off);
    __shared__ float sm[2];
    if ((b & 63) == 0) sm[b >> 6] = part;
    __syncthreads();
    if (b == 0) out[0] = (sm[0] + sm[1]) * (1.0f / NB);
}

extern "C" void kernel_launch(void* const* d_in, const int* in_sizes, int n_in,
                              void* d_out, int out_size, void* d_ws, size_t ws_size,
                              hipStream_t stream)
{
    const int*   inputs = (const int*)d_in[0];
    const int*   tags   = (const int*)d_in[1];
    // d_in[2] = mask: all-true, unused
    const float* emb    = (const float*)d_in[3];
    const float* Wih_f  = (const float*)d_in[4];
    const float* Whh_f  = (const float*)d_in[5];
    const float* b_f    = (const float*)d_in[6];
    const float* Wih_b  = (const float*)d_in[7];
    const float* Whh_b  = (const float*)d_in[8];
    const float* b_b    = (const float*)d_in[9];
    const float* W_out  = (const float*)d_in[10];
    const float* b_out  = (const float*)d_in[11];
    const float* startv = (const float*)d_in[12];
    const float* endv   = (const float*)d_in[13];
    const float* transv = (const float*)d_in[14];

    char* w = (char*)d_ws;
    unsigned short* xg = (unsigned short*)w; w += (size_t)SB * NB * 512 * 2;  // 67.1 MB
    float* h_all = (float*)w;                w += (size_t)SB * NB * 128 * 4;  // 33.6 MB
    float* em2   = (float*)w;                w += (size_t)SB * 9 * NB * 4;    //  2.4 MB
    float* W2    = (float*)w;                w += 512 * 100 * 4;
    float* bias2 = (float*)w;                w += 512 * 4;
    int*   tagsT = (int*)w;                  w += (size_t)SB * NB * 4;

    prep_kernel<<<458, 256, 0, stream>>>(tags, Wih_f, Wih_b, b_f, b_b, W2, bias2, tagsT);
    gemm_kernel<<<2048, 256, 0, stream>>>(inputs, emb, W2, bias2, xg);
    lstm_kernel<<<256, 64, 0, stream>>>(xg, Whh_f, Whh_b, h_all);
    proj_kernel<<<SB, 128, 0, stream>>>(h_all, W_out, b_out, em2);
    crf_kernel<<<1, 128, 0, stream>>>(em2, tagsT, startv, endv, transv, (float*)d_out);
}

// Round 3
// 763.437 us; speedup vs baseline: 1.5436x; 1.5436x over previous
//
#include <hip/hip_runtime.h>
#include <math.h>

#define SB 512
#define NB 128
#define NE 100
#define HD 64
#define NK 9

typedef _Float16 h2 __attribute__((ext_vector_type(2)));
union U4 { uint4 u; h2 h[4]; _Float16 f[8]; };
union U2 { uint2 u; _Float16 f[4]; };
union UH { unsigned u; _Float16 f[2]; };

__device__ __forceinline__ float frcp(float x) { return __builtin_amdgcn_rcpf(x); }
__device__ __forceinline__ float fsig(float x) { return frcp(1.0f + __expf(-x)); }
__device__ __forceinline__ float ftanh(float x) {
    float t = __expf(-2.0f * fabsf(x));
    float r = (1.0f - t) * frcp(1.0f + t);
    return copysignf(r, x);
}
__device__ __forceinline__ float fdot2(h2 a, h2 b, float c) {
    return __builtin_amdgcn_fdot2(a, b, c, false);
}

// ---------------------------------------------------------------------------
// prep: pack W2h (input-GEMM weights, f16 pairs, K padded 100->104),
//       whh_h (recurrent weights, f16 pairs, [dir][gate][k4][j] uint4-coalesced),
//       bias2, tagsT.
// col = dir*256 + j*4 + g  maps to Wih row (g*64+j).
// ---------------------------------------------------------------------------
__global__ void prep_kernel(const int* __restrict__ tags,
                            const float* __restrict__ Wih_f, const float* __restrict__ Wih_bb,
                            const float* __restrict__ Whh_f, const float* __restrict__ Whh_bb,
                            const float* __restrict__ b_f, const float* __restrict__ b_bb,
                            unsigned* __restrict__ W2h, unsigned* __restrict__ whh_h,
                            float* __restrict__ bias2, int* __restrict__ tagsT)
{
    int idx = blockIdx.x * 256 + threadIdx.x;
    if (idx < 26624) {                       // W2h: [512 cols][52 half2-dwords]
        int col = idx / 52, d = idx - col * 52;
        int dir = col >> 8, r = col & 255, j = r >> 2, g = r & 3;
        const float* src = (dir ? Wih_bb : Wih_f) + (g * 64 + j) * 100;
        UH u; u.u = 0;
        if (d < 50) { u.f[0] = (_Float16)src[2 * d]; u.f[1] = (_Float16)src[2 * d + 1]; }
        W2h[idx] = u.u;
    } else if (idx < 43008) {                // whh_h: dword (( (dir*4+g)*8 + k4 )*64 + j)*4 + q
        int i2 = idx - 26624;
        int q = i2 & 3, j = (i2 >> 2) & 63, k4 = (i2 >> 8) & 7, g = (i2 >> 11) & 3, dir = i2 >> 13;
        int p = k4 * 4 + q;                  // half2 pair index -> k = 2p, 2p+1
        const float* src = (dir ? Whh_bb : Whh_f) + (g * 64 + j) * 64 + 2 * p;
        UH u; u.f[0] = (_Float16)src[0]; u.f[1] = (_Float16)src[1];
        whh_h[(((dir * 4 + g) * 8 + k4) * 64 + j) * 4 + q] = u.u;
    } else if (idx < 43520) {                // bias2
        int col = idx - 43008;
        int dir = col >> 8, r = col & 255, j = r >> 2, g = r & 3;
        bias2[col] = (dir ? b_bb : b_f)[g * 64 + j];
    } else if (idx < 109056) {               // tagsT[t][b]
        int i4 = idx - 43520;
        int t = i4 >> 7, b = i4 & 127;
        tagsT[i4] = tags[b * SB + t] - 1;
    }
}

// ---------------------------------------------------------------------------
// input GEMM (f16 dot2): xgh[tb][512] = emb[token(t,b)] . W2^T + bias2
// tile: 128 rows (all b of one t) x 128 cols; 8x8 register blocking; K=104
// ---------------------------------------------------------------------------
__global__ __launch_bounds__(256, 1) void gemm_kernel(
    const int* __restrict__ inputs, const float* __restrict__ emb,
    const unsigned* __restrict__ W2h, const float* __restrict__ bias2,
    _Float16* __restrict__ xgh)
{
    __shared__ __align__(16) unsigned sE[128 * 52];
    __shared__ __align__(16) unsigned sW[128 * 52];
    __shared__ int stok[128];
    const int bx = blockIdx.x;
    const int tt = bx >> 2;
    const int cb = (bx & 3) * 128;
    const int tid = threadIdx.x;

    if (tid < 128) stok[tid] = inputs[tid * SB + tt];
    for (int idx = tid; idx < 1664; idx += 256)
        ((uint4*)sW)[idx] = ((const uint4*)W2h)[cb * 13 + idx];
    __syncthreads();
    for (int idx = tid; idx < 6656; idx += 256) {
        int row = idx / 52, d = idx - row * 52;
        int token = stok[row];
        UH u; u.u = 0;
        if (d < 50) {
            const float* ep = emb + (size_t)token * 100 + 2 * d;
            u.f[0] = (_Float16)ep[0]; u.f[1] = (_Float16)ep[1];
        }
        sE[idx] = u.u;
    }
    __syncthreads();

    const int tx = tid & 15, ty = tid >> 4;
    float acc[8][8];
    #pragma unroll
    for (int r = 0; r < 8; ++r)
        #pragma unroll
        for (int i = 0; i < 8; ++i) acc[r][i] = 0.f;

    for (int kk = 0; kk < 13; ++kk) {
        U4 e[8], wv[8];
        #pragma unroll
        for (int r = 0; r < 8; ++r) e[r].u = ((const uint4*)sE)[(ty + 16 * r) * 13 + kk];
        #pragma unroll
        for (int i = 0; i < 8; ++i) wv[i].u = ((const uint4*)sW)[(tx + 16 * i) * 13 + kk];
        #pragma unroll
        for (int r = 0; r < 8; ++r)
            #pragma unroll
            for (int i = 0; i < 8; ++i) {
                float a = acc[r][i];
                #pragma unroll
                for (int q = 0; q < 4; ++q) a = fdot2(e[r].h[q], wv[i].h[q], a);
                acc[r][i] = a;
            }
    }

    #pragma unroll
    for (int i = 0; i < 8; ++i) {
        int col = cb + tx + 16 * i;
        float bc = bias2[col];
        #pragma unroll
        for (int r = 0; r < 8; ++r) {
            int row = tt * NB + ty + 16 * r;
            xgh[(size_t)row * 512 + col] = (_Float16)(acc[r][i] + bc);
        }
    }
}

// ---------------------------------------------------------------------------
// LSTM recurrence: 256 blocks (b,dir) x 64 lanes (single wave). Lane j = unit j.
// Whh in f16 pairs: 128 VGPRs (4 gates x 8 uint4). h broadcast via f16 LDS.
// ---------------------------------------------------------------------------
__global__ __launch_bounds__(64, 1) void lstm_kernel(
    const _Float16* __restrict__ xgh, const unsigned* __restrict__ whh_h,
    float* __restrict__ h_all)
{
    const int blk = blockIdx.x;
    const int b = blk & (NB - 1);
    const int dir = blk >> 7;
    const int j = threadIdx.x;

    U4 w[4][8];
    const uint4* W4 = (const uint4*)whh_h;
    #pragma unroll
    for (int g = 0; g < 4; ++g)
        #pragma unroll
        for (int k4 = 0; k4 < 8; ++k4)
            w[g][k4].u = W4[((dir * 4 + g) * 8 + k4) * 64 + j];

    __shared__ __align__(16) _Float16 hbuf[64];
    hbuf[j] = (_Float16)0.f;
    float c = 0.f;

#define XOFF(s) (((size_t)((dir ? (SB - 1 - (s)) : (s)) * NB + b)) * 512 + dir * 256 + j * 4)
    U2 p0, p1;
    p0.u = *(const uint2*)(xgh + XOFF(0));
    p1.u = *(const uint2*)(xgh + XOFF(1));
    __syncthreads();

    for (int s = 0; s < SB; ++s) {
        const int t = dir ? (SB - 1 - s) : s;
        float a0 = (float)p0.f[0], a1 = (float)p0.f[1];
        float a2 = (float)p0.f[2], a3 = (float)p0.f[3];
        p0 = p1;
        if (s + 2 < SB) p1.u = *(const uint2*)(xgh + XOFF(s + 2));

        U4 hv[8];
        #pragma unroll
        for (int k4 = 0; k4 < 8; ++k4) hv[k4].u = ((const uint4*)hbuf)[k4];
        #pragma unroll
        for (int k4 = 0; k4 < 8; ++k4)
            #pragma unroll
            for (int q = 0; q < 4; ++q) {
                a0 = fdot2(hv[k4].h[q], w[0][k4].h[q], a0);
                a1 = fdot2(hv[k4].h[q], w[1][k4].h[q], a1);
                a2 = fdot2(hv[k4].h[q], w[2][k4].h[q], a2);
                a3 = fdot2(hv[k4].h[q], w[3][k4].h[q], a3);
            }

        float ig = fsig(a0), fg = fsig(a1), gg = ftanh(a2), og = fsig(a3);
        c = fg * c + ig * gg;
        float h = og * ftanh(c);
        h_all[((size_t)t * NB + b) * 128 + dir * HD + j] = h;
        hbuf[j] = (_Float16)h;
        __syncthreads();
    }
#undef XOFF
}

// ---------------------------------------------------------------------------
// projection: em2[t][k][b] = h_all[t][b][:] . W_out[k+1][:] + b_out[k+1]
// ---------------------------------------------------------------------------
__global__ __launch_bounds__(128) void proj_kernel(
    const float* __restrict__ h_all, const float* __restrict__ W_out,
    const float* __restrict__ b_out, float* __restrict__ em2)
{
    __shared__ __align__(16) float sWo[9 * 128];
    __shared__ float sb[9];
    const int t = blockIdx.x, b = threadIdx.x;
    for (int idx = b; idx < 1152; idx += 128) sWo[idx] = W_out[128 + idx];
    if (b < 9) sb[b] = b_out[1 + b];
    __syncthreads();

    const float4* h4 = (const float4*)(h_all + ((size_t)t * NB + b) * 128);
    float acc[9];
    #pragma unroll
    for (int k = 0; k < 9; ++k) acc[k] = 0.f;
    for (int q = 0; q < 32; ++q) {
        float4 hv = h4[q];
        #pragma unroll
        for (int k = 0; k < 9; ++k) {
            float4 wv = ((const float4*)sWo)[k * 32 + q];
            acc[k] += hv.x * wv.x + hv.y * wv.y + hv.z * wv.z + hv.w * wv.w;
        }
    }
    #pragma unroll
    for (int k = 0; k < 9; ++k)
        em2[((size_t)t * 9 + k) * NB + b] = acc[k] + sb[k];
}

// ---------------------------------------------------------------------------
// CRF: lane b = one chain. Linear-space alpha, exp(trans) in regs, renorm /8.
// Depth-2 software pipeline on em2/tags loads to hide L2/L3 latency.
// ---------------------------------------------------------------------------
__device__ __forceinline__ float pick9(const float e[9], int k) {
    float r = e[0];
    r = (k == 1) ? e[1] : r;  r = (k == 2) ? e[2] : r;
    r = (k == 3) ? e[3] : r;  r = (k == 4) ? e[4] : r;
    r = (k == 5) ? e[5] : r;  r = (k == 6) ? e[6] : r;
    r = (k == 7) ? e[7] : r;  r = (k == 8) ? e[8] : r;
    return r;
}

__global__ __launch_bounds__(128, 1) void crf_kernel(
    const float* __restrict__ em2, const int* __restrict__ tagsT,
    const float* __restrict__ startv, const float* __restrict__ endv,
    const float* __restrict__ trans, float* __restrict__ out)
{
    const int b = threadIdx.x;
    float E[81];
    #pragma unroll
    for (int i = 0; i < 81; ++i) E[i] = __expf(trans[i]);

    float A[9], M = 0.f, score;
    int tg;
    {
        float cur[9];
        #pragma unroll
        for (int k = 0; k < 9; ++k) cur[k] = em2[(size_t)k * NB + b];
        tg = tagsT[b];
        score = startv[tg] + pick9(cur, tg);
        #pragma unroll
        for (int k = 0; k < 9; ++k) A[k] = __expf(startv[k] + cur[k]);
    }

#define CRF_LOAD(EB, GT, T) do {                                          \
        _Pragma("unroll")                                                 \
        for (int k = 0; k < 9; ++k) EB[k] = em2[((size_t)(T) * 9 + k) * NB + b]; \
        GT = tagsT[(T) * NB + b];                                         \
    } while (0)

#define CRF_STEP(EB, GT, T) do {                                          \
        int etg = GT;                                                     \
        score += trans[tg * 9 + etg] + pick9(EB, etg);                    \
        tg = etg;                                                         \
        float ex[9], snew[9];                                             \
        _Pragma("unroll")                                                 \
        for (int k = 0; k < 9; ++k) ex[k] = __expf(EB[k]);                \
        _Pragma("unroll")                                                 \
        for (int k = 0; k < 9; ++k) snew[k] = 0.f;                        \
        _Pragma("unroll")                                                 \
        for (int i = 0; i < 9; ++i)                                       \
            _Pragma("unroll")                                             \
            for (int k = 0; k < 9; ++k) snew[k] += A[i] * E[i * 9 + k];   \
        _Pragma("unroll")                                                 \
        for (int k = 0; k < 9; ++k) A[k] = snew[k] * ex[k];               \
        if (((T) & 7) == 0) {                                             \
            float mx = A[0];                                              \
            _Pragma("unroll")                                             \
            for (int k = 1; k < 9; ++k) mx = fmaxf(mx, A[k]);             \
            M += __logf(mx);                                              \
            float rr = frcp(mx);                                          \
            _Pragma("unroll")                                             \
            for (int k = 0; k < 9; ++k) A[k] *= rr;                       \
        }                                                                 \
    } while (0)

    float eA[9], eB[9];
    int gA, gB;
    CRF_LOAD(eA, gA, 1);
    CRF_LOAD(eB, gB, 2);

    for (int t = 1; t < SB; t += 2) {
        CRF_STEP(eA, gA, t);
        if (t + 2 < SB) CRF_LOAD(eA, gA, t + 2);
        if (t + 1 < SB) {
            CRF_STEP(eB, gB, t + 1);
            if (t + 3 < SB) CRF_LOAD(eB, gB, t + 3);
        }
    }

    score += endv[tg];
    float Z = 0.f;
    #pragma unroll
    for (int k = 0; k < 9; ++k) Z += A[k] * __expf(endv[k]);
    float part = M + __logf(Z) - score;

    #pragma unroll
    for (int off = 32; off > 0; off >>= 1) part += __shfl_down(part, off);
    __shared__ float sm[2];
    if ((b & 63) == 0) sm[b >> 6] = part;
    __syncthreads();
    if (b == 0) out[0] = (sm[0] + sm[1]) * (1.0f / NB);
#undef CRF_LOAD
#undef CRF_STEP
}

extern "C" void kernel_launch(void* const* d_in, const int* in_sizes, int n_in,
                              void* d_out, int out_size, void* d_ws, size_t ws_size,
                              hipStream_t stream)
{
    const int*   inputs = (const int*)d_in[0];
    const int*   tags   = (const int*)d_in[1];
    // d_in[2] = mask: all-true, unused
    const float* emb    = (const float*)d_in[3];
    const float* Wih_f  = (const float*)d_in[4];
    const float* Whh_f  = (const float*)d_in[5];
    const float* b_f    = (const float*)d_in[6];
    const float* Wih_b  = (const float*)d_in[7];
    const float* Whh_b  = (const float*)d_in[8];
    const float* b_b    = (const float*)d_in[9];
    const float* W_out  = (const float*)d_in[10];
    const float* b_out  = (const float*)d_in[11];
    const float* startv = (const float*)d_in[12];
    const float* endv   = (const float*)d_in[13];
    const float* transv = (const float*)d_in[14];

    char* w = (char*)d_ws;
    _Float16* xgh  = (_Float16*)w;  w += (size_t)SB * NB * 512 * 2;   // 67.1 MB
    float* h_all   = (float*)w;     w += (size_t)SB * NB * 128 * 4;   // 33.6 MB
    float* em2     = (float*)w;     w += (size_t)SB * 9 * NB * 4;     //  2.4 MB
    unsigned* W2h  = (unsigned*)w;  w += 26624 * 4;
    unsigned* whh  = (unsigned*)w;  w += 16384 * 4;
    float* bias2   = (float*)w;     w += 512 * 4;
    int* tagsT     = (int*)w;       w += (size_t)SB * NB * 4;

    prep_kernel<<<426, 256, 0, stream>>>(tags, Wih_f, Wih_b, Whh_f, Whh_b, b_f, b_b,
                                         W2h, whh, bias2, tagsT);
    gemm_kernel<<<2048, 256, 0, stream>>>(inputs, emb, W2h, bias2, xgh);
    lstm_kernel<<<256, 64, 0, stream>>>(xgh, whh, h_all);
    proj_kernel<<<SB, 128, 0, stream>>>(h_all, W_out, b_out, em2);
    crf_kernel<<<1, 128, 0, stream>>>(em2, tagsT, startv, endv, transv, (float*)d_out);
}

// Round 4
// 531.042 us; speedup vs baseline: 2.2191x; 1.4376x over previous
//
#include <hip/hip_runtime.h>
#include <math.h>

#define SB 512
#define NB 128
#define HD 64

typedef _Float16 h2 __attribute__((ext_vector_type(2)));
union U4 { uint4 u; h2 h[4]; _Float16 f[8]; };
union U2 { uint2 u; _Float16 f[4]; };
union UH { unsigned u; _Float16 f[2]; };

__device__ __forceinline__ float frcp(float x) { return __builtin_amdgcn_rcpf(x); }
__device__ __forceinline__ float fsig(float x) { return frcp(1.0f + __expf(-x)); }
__device__ __forceinline__ float ftanh(float x) {
    float t = __expf(-2.0f * fabsf(x));
    float r = (1.0f - t) * frcp(1.0f + t);
    return copysignf(r, x);
}
__device__ __forceinline__ float fdot2(h2 a, h2 b, float c) {
    return __builtin_amdgcn_fdot2(a, b, c, false);
}

// ---------------------------------------------------------------------------
// prep: W2h (input GEMM weights f16, K 100->104), whh_h (recurrent f16,
// [dir][gate][k4][j][q] uint4-coalesced), bias2, Eexp = exp(trans).
// col = dir*256 + j*4 + g maps to Wih row (g*64+j).
// ---------------------------------------------------------------------------
__global__ void prep_kernel(const float* __restrict__ Wih_f, const float* __restrict__ Wih_bb,
                            const float* __restrict__ Whh_f, const float* __restrict__ Whh_bb,
                            const float* __restrict__ b_f, const float* __restrict__ b_bb,
                            const float* __restrict__ trans,
                            unsigned* __restrict__ W2h, unsigned* __restrict__ whh_h,
                            float* __restrict__ bias2, float* __restrict__ Eexp)
{
    int idx = blockIdx.x * 256 + threadIdx.x;
    if (idx < 26624) {                       // W2h: [512 cols][52 half2-dwords]
        int col = idx / 52, d = idx - col * 52;
        int dir = col >> 8, r = col & 255, j = r >> 2, g = r & 3;
        const float* src = (dir ? Wih_bb : Wih_f) + (g * 64 + j) * 100;
        UH u; u.u = 0;
        if (d < 50) { u.f[0] = (_Float16)src[2 * d]; u.f[1] = (_Float16)src[2 * d + 1]; }
        W2h[idx] = u.u;
    } else if (idx < 43008) {                // whh_h
        int i2 = idx - 26624;
        int q = i2 & 3, j = (i2 >> 2) & 63, k4 = (i2 >> 8) & 7, g = (i2 >> 11) & 3, dir = i2 >> 13;
        int p = k4 * 4 + q;
        const float* src = (dir ? Whh_bb : Whh_f) + (g * 64 + j) * 64 + 2 * p;
        UH u; u.f[0] = (_Float16)src[0]; u.f[1] = (_Float16)src[1];
        whh_h[(((dir * 4 + g) * 8 + k4) * 64 + j) * 4 + q] = u.u;
    } else if (idx < 43520) {                // bias2
        int col = idx - 43008;
        int dir = col >> 8, r = col & 255, j = r >> 2, g = r & 3;
        bias2[col] = (dir ? b_bb : b_f)[g * 64 + j];
    } else if (idx < 43601) {                // Eexp = exp(trans), 81
        int i = idx - 43520;
        Eexp[i] = __expf(trans[i]);
    }
}

// ---------------------------------------------------------------------------
// input GEMM (f16 dot2): xgh[tb][512] = emb[token(t,b)] . W2^T + bias2
// ---------------------------------------------------------------------------
__global__ __launch_bounds__(256, 1) void gemm_kernel(
    const int* __restrict__ inputs, const float* __restrict__ emb,
    const unsigned* __restrict__ W2h, const float* __restrict__ bias2,
    _Float16* __restrict__ xgh)
{
    __shared__ __align__(16) unsigned sE[128 * 52];
    __shared__ __align__(16) unsigned sW[128 * 52];
    __shared__ int stok[128];
    const int bx = blockIdx.x;
    const int tt = bx >> 2;
    const int cb = (bx & 3) * 128;
    const int tid = threadIdx.x;

    if (tid < 128) stok[tid] = inputs[tid * SB + tt];
    for (int idx = tid; idx < 1664; idx += 256)
        ((uint4*)sW)[idx] = ((const uint4*)W2h)[cb * 13 + idx];
    __syncthreads();
    for (int idx = tid; idx < 6656; idx += 256) {
        int row = idx / 52, d = idx - row * 52;
        int token = stok[row];
        UH u; u.u = 0;
        if (d < 50) {
            const float* ep = emb + (size_t)token * 100 + 2 * d;
            u.f[0] = (_Float16)ep[0]; u.f[1] = (_Float16)ep[1];
        }
        sE[idx] = u.u;
    }
    __syncthreads();

    const int tx = tid & 15, ty = tid >> 4;
    float acc[8][8];
    #pragma unroll
    for (int r = 0; r < 8; ++r)
        #pragma unroll
        for (int i = 0; i < 8; ++i) acc[r][i] = 0.f;

    for (int kk = 0; kk < 13; ++kk) {
        U4 e[8], wv[8];
        #pragma unroll
        for (int r = 0; r < 8; ++r) e[r].u = ((const uint4*)sE)[(ty + 16 * r) * 13 + kk];
        #pragma unroll
        for (int i = 0; i < 8; ++i) wv[i].u = ((const uint4*)sW)[(tx + 16 * i) * 13 + kk];
        #pragma unroll
        for (int r = 0; r < 8; ++r)
            #pragma unroll
            for (int i = 0; i < 8; ++i) {
                float a = acc[r][i];
                #pragma unroll
                for (int q = 0; q < 4; ++q) a = fdot2(e[r].h[q], wv[i].h[q], a);
                acc[r][i] = a;
            }
    }

    #pragma unroll
    for (int i = 0; i < 8; ++i) {
        int col = cb + tx + 16 * i;
        float bc = bias2[col];
        #pragma unroll
        for (int r = 0; r < 8; ++r) {
            int row = tt * NB + ty + 16 * r;
            xgh[(size_t)row * 512 + col] = (_Float16)(acc[r][i] + bc);
        }
    }
}

// ---------------------------------------------------------------------------
// LSTM recurrence: 256 blocks (b,dir) x 64 lanes. Pointer-walked addresses;
// unconditional prefetch (overruns land in adjacent ws regions, never used).
// ---------------------------------------------------------------------------
__global__ __launch_bounds__(64, 1) void lstm_kernel(
    const _Float16* __restrict__ xgh, const unsigned* __restrict__ whh_h,
    float* __restrict__ h_all)
{
    const int blk = blockIdx.x;
    const int b = blk & (NB - 1);
    const int dir = blk >> 7;
    const int j = threadIdx.x;

    U4 w[4][8];
    const uint4* W4 = (const uint4*)whh_h;
    #pragma unroll
    for (int g = 0; g < 4; ++g)
        #pragma unroll
        for (int k4 = 0; k4 < 8; ++k4)
            w[g][k4].u = W4[((dir * 4 + g) * 8 + k4) * 64 + j];

    __shared__ __align__(16) _Float16 hbuf[64];
    hbuf[j] = (_Float16)0.f;
    float c = 0.f;

    const int t0 = dir ? (SB - 1) : 0;
    const ptrdiff_t xstride = (dir ? -1 : 1) * (ptrdiff_t)(NB * 512);
    const ptrdiff_t hstride = (dir ? -1 : 1) * (ptrdiff_t)(NB * 128);
    const _Float16* xp = xgh + ((size_t)(t0 * NB + b)) * 512 + dir * 256 + j * 4;
    float* hp = h_all + ((size_t)(t0 * NB + b)) * 128 + dir * HD + j;

    U2 p0, p1;
    p0.u = *(const uint2*)xp;
    p1.u = *(const uint2*)(xp + xstride);
    const _Float16* xq = xp + 2 * xstride;
    __syncthreads();

    for (int s = 0; s < SB; ++s) {
        float a0 = (float)p0.f[0], a1 = (float)p0.f[1];
        float a2 = (float)p0.f[2], a3 = (float)p0.f[3];
        p0 = p1;
        p1.u = *(const uint2*)xq;       // unconditional; last 2 reads are slack
        xq += xstride;

        U4 hv[8];
        #pragma unroll
        for (int k4 = 0; k4 < 8; ++k4) hv[k4].u = ((const uint4*)hbuf)[k4];
        #pragma unroll
        for (int k4 = 0; k4 < 8; ++k4)
            #pragma unroll
            for (int q = 0; q < 4; ++q) {
                a0 = fdot2(hv[k4].h[q], w[0][k4].h[q], a0);
                a1 = fdot2(hv[k4].h[q], w[1][k4].h[q], a1);
                a2 = fdot2(hv[k4].h[q], w[2][k4].h[q], a2);
                a3 = fdot2(hv[k4].h[q], w[3][k4].h[q], a3);
            }

        float ig = fsig(a0), fg = fsig(a1), gg = ftanh(a2), og = fsig(a3);
        c = fg * c + ig * gg;
        float h = og * ftanh(c);
        *hp = h;
        hp += hstride;
        hbuf[j] = (_Float16)h;
        __syncthreads();
    }
}

// ---------------------------------------------------------------------------
// projection: em3[b][t*12 + k] = h_all[t][b][:] . W_out[k+1][:] + b_out[k+1]
// ---------------------------------------------------------------------------
__global__ __launch_bounds__(128) void proj_kernel(
    const float* __restrict__ h_all, const float* __restrict__ W_out,
    const float* __restrict__ b_out, float* __restrict__ em3)
{
    __shared__ __align__(16) float sWo[9 * 128];
    __shared__ float sb[9];
    const int t = blockIdx.x, b = threadIdx.x;
    for (int idx = b; idx < 1152; idx += 128) sWo[idx] = W_out[128 + idx];
    if (b < 9) sb[b] = b_out[1 + b];
    __syncthreads();

    const float4* h4 = (const float4*)(h_all + ((size_t)t * NB + b) * 128);
    float acc[9];
    #pragma unroll
    for (int k = 0; k < 9; ++k) acc[k] = 0.f;
    for (int q = 0; q < 32; ++q) {
        float4 hv = h4[q];
        #pragma unroll
        for (int k = 0; k < 9; ++k) {
            float4 wv = ((const float4*)sWo)[k * 32 + q];
            acc[k] += hv.x * wv.x + hv.y * wv.y + hv.z * wv.z + hv.w * wv.w;
        }
    }
    float* dst = em3 + (size_t)b * (SB * 12) + t * 12;
    #pragma unroll
    for (int k = 0; k < 9; ++k) dst[k] = acc[k] + sb[k];
}

// ---------------------------------------------------------------------------
// CRF gold-path score: block = batch, 64 lanes strided over t, shuffle-reduce.
// ---------------------------------------------------------------------------
__global__ __launch_bounds__(64, 1) void crf_gold(
    const float* __restrict__ em3, const int* __restrict__ tags,
    const float* __restrict__ startv, const float* __restrict__ endv,
    const float* __restrict__ trans, float* __restrict__ gold)
{
    const int b = blockIdx.x, l = threadIdx.x;
    const int* tb = tags + (size_t)b * SB;
    const float* eb = em3 + (size_t)b * (SB * 12);
    float sc = 0.f;
    for (int t = l; t < SB; t += 64) {
        int tg = tb[t] - 1;
        if (t > 0) {
            int tp = tb[t - 1] - 1;
            sc += trans[tp * 9 + tg] + eb[t * 12 + tg];
        }
    }
    if (l == 0) {
        int tg0 = tb[0] - 1, tgl = tb[SB - 1] - 1;
        sc += startv[tg0] + eb[tg0] + endv[tgl];
    }
    #pragma unroll
    for (int off = 32; off > 0; off >>= 1) sc += __shfl_down(sc, off);
    if (l == 0) gold[b] = sc;
}

// ---------------------------------------------------------------------------
// CRF parallel scan: lane = (b, chunk); chunk c covers t in [1+16c, 1+16c+16).
// P = prod of M_t (9x9, linear space), renorm every 4 steps, log-scale in M.
// Pws layout: [(b*32+c)][84]  (81 P entries + logscale + pad)
// ---------------------------------------------------------------------------
__global__ __launch_bounds__(256, 1) void crf_scan(
    const float* __restrict__ em3, const float* __restrict__ Eexp,
    float* __restrict__ Pws)
{
    const int lane = blockIdx.x * 256 + threadIdx.x;   // 0..4095
    const int c = lane & 31, b = lane >> 5;

    float E[81];
    #pragma unroll
    for (int i = 0; i < 81; ++i) E[i] = Eexp[i];

    float P[81];
    #pragma unroll
    for (int i = 0; i < 81; ++i) P[i] = 0.f;
    #pragma unroll
    for (int i = 0; i < 9; ++i) P[i * 9 + i] = 1.f;
    float M = 0.f;

    const int t0 = 1 + 16 * c;
    const int nst = (t0 + 16 <= SB) ? 16 : (SB - t0);
    const float* ep = em3 + (size_t)b * (SB * 12) + t0 * 12;

    for (int s = 0; s < nst; ++s, ep += 12) {
        float4 e0 = *(const float4*)ep;
        float4 e1 = *(const float4*)(ep + 4);
        float e8 = ep[8];
        float ex[9] = { __expf(e0.x), __expf(e0.y), __expf(e0.z), __expf(e0.w),
                        __expf(e1.x), __expf(e1.y), __expf(e1.z), __expf(e1.w),
                        __expf(e8) };
        #pragma unroll
        for (int i = 0; i < 9; ++i) {
            float tmp[9];
            #pragma unroll
            for (int jj = 0; jj < 9; ++jj) tmp[jj] = P[i * 9] * E[jj];
            #pragma unroll
            for (int k = 1; k < 9; ++k)
                #pragma unroll
                for (int jj = 0; jj < 9; ++jj) tmp[jj] += P[i * 9 + k] * E[k * 9 + jj];
            #pragma unroll
            for (int jj = 0; jj < 9; ++jj) P[i * 9 + jj] = tmp[jj] * ex[jj];
        }
        if ((s & 3) == 3) {
            float mx = P[0];
            #pragma unroll
            for (int i = 1; i < 81; ++i) mx = fmaxf(mx, P[i]);
            M += __logf(mx);
            float r = frcp(mx);
            #pragma unroll
            for (int i = 0; i < 81; ++i) P[i] *= r;
        }
    }

    float* dst = Pws + (size_t)lane * 84;
    #pragma unroll
    for (int i = 0; i < 81; ++i) dst[i] = P[i];
    dst[81] = M;
}

// ---------------------------------------------------------------------------
// CRF combine: 128 lanes (b). alpha0 swept through 32 chunk matrices; logZ;
// part = logZ - gold; mean over batch.
// ---------------------------------------------------------------------------
__global__ __launch_bounds__(128, 1) void crf_combine(
    const float* __restrict__ em3, const float* __restrict__ Pws,
    const float* __restrict__ gold, const float* __restrict__ startv,
    const float* __restrict__ endv, float* __restrict__ out)
{
    const int b = threadIdx.x;
    float A[9], M = 0.f;
    {
        const float* eb = em3 + (size_t)b * (SB * 12);
        float4 e0 = *(const float4*)eb;
        float4 e1 = *(const float4*)(eb + 4);
        float e[9] = { e0.x, e0.y, e0.z, e0.w, e1.x, e1.y, e1.z, e1.w, eb[8] };
        #pragma unroll
        for (int k = 0; k < 9; ++k) A[k] = __expf(startv[k] + e[k]);
    }

    for (int c = 0; c < 32; ++c) {
        const float4* src = (const float4*)(Pws + ((size_t)b * 32 + c) * 84);
        float buf[84];
        #pragma unroll
        for (int q = 0; q < 21; ++q) {
            float4 v = src[q];
            buf[4 * q] = v.x; buf[4 * q + 1] = v.y; buf[4 * q + 2] = v.z; buf[4 * q + 3] = v.w;
        }
        float tmp[9];
        #pragma unroll
        for (int jj = 0; jj < 9; ++jj) tmp[jj] = A[0] * buf[jj];
        #pragma unroll
        for (int i = 1; i < 9; ++i)
            #pragma unroll
            for (int jj = 0; jj < 9; ++jj) tmp[jj] += A[i] * buf[i * 9 + jj];
        float mx = tmp[0];
        #pragma unroll
        for (int jj = 1; jj < 9; ++jj) mx = fmaxf(mx, tmp[jj]);
        M += __logf(mx) + buf[81];
        float r = frcp(mx);
        #pragma unroll
        for (int jj = 0; jj < 9; ++jj) A[jj] = tmp[jj] * r;
    }

    float Z = 0.f;
    #pragma unroll
    for (int k = 0; k < 9; ++k) Z += A[k] * __expf(endv[k]);
    float part = M + __logf(Z) - gold[b];

    #pragma unroll
    for (int off = 32; off > 0; off >>= 1) part += __shfl_down(part, off);
    __shared__ float sm[2];
    if ((b & 63) == 0) sm[b >> 6] = part;
    __syncthreads();
    if (b == 0) out[0] = (sm[0] + sm[1]) * (1.0f / NB);
}

extern "C" void kernel_launch(void* const* d_in, const int* in_sizes, int n_in,
                              void* d_out, int out_size, void* d_ws, size_t ws_size,
                              hipStream_t stream)
{
    const int*   inputs = (const int*)d_in[0];
    const int*   tags   = (const int*)d_in[1];
    // d_in[2] = mask: all-true, unused
    const float* emb    = (const float*)d_in[3];
    const float* Wih_f  = (const float*)d_in[4];
    const float* Whh_f  = (const float*)d_in[5];
    const float* b_f    = (const float*)d_in[6];
    const float* Wih_b  = (const float*)d_in[7];
    const float* Whh_b  = (const float*)d_in[8];
    const float* b_b    = (const float*)d_in[9];
    const float* W_out  = (const float*)d_in[10];
    const float* b_out  = (const float*)d_in[11];
    const float* startv = (const float*)d_in[12];
    const float* endv   = (const float*)d_in[13];
    const float* transv = (const float*)d_in[14];

    char* w = (char*)d_ws;
    float* h_all   = (float*)w;     w += (size_t)SB * NB * 128 * 4;   // 33.6 MB (also pre-slack for lstm prefetch)
    _Float16* xgh  = (_Float16*)w;  w += (size_t)SB * NB * 512 * 2;   // 67.1 MB
    float* em3     = (float*)w;     w += (size_t)NB * SB * 12 * 4;    //  3.1 MB (also post-slack)
    float* Pws     = (float*)w;     w += (size_t)NB * 32 * 84 * 4;    //  1.4 MB
    float* gold    = (float*)w;     w += NB * 4;
    unsigned* W2h  = (unsigned*)w;  w += 26624 * 4;
    unsigned* whh  = (unsigned*)w;  w += 16384 * 4;
    float* bias2   = (float*)w;     w += 512 * 4;
    float* Eexp    = (float*)w;     w += 81 * 4;

    prep_kernel<<<171, 256, 0, stream>>>(Wih_f, Wih_b, Whh_f, Whh_b, b_f, b_b, transv,
                                         W2h, whh, bias2, Eexp);
    gemm_kernel<<<2048, 256, 0, stream>>>(inputs, emb, W2h, bias2, xgh);
    lstm_kernel<<<256, 64, 0, stream>>>(xgh, whh, h_all);
    proj_kernel<<<SB, 128, 0, stream>>>(h_all, W_out, b_out, em3);
    crf_gold<<<NB, 64, 0, stream>>>(em3, tags, startv, endv, transv, gold);
    crf_scan<<<16, 256, 0, stream>>>(em3, Eexp, Pws);
    crf_combine<<<1, 128, 0, stream>>>(em3, Pws, gold, startv, endv, (float*)d_out);
}